// Round 13
// baseline (236.544 us; speedup 1.0000x reference)
//
#include <hip/hip_runtime.h>

#define BB 2
#define LL 2048
#define DDIM 1024
#define HH 16
#define HDIM 64
#define MM (BB*LL)   // 4096
#define KK 1024
#define LOG2E 1.44269504f

typedef __attribute__((ext_vector_type(8))) short s8v;
typedef __attribute__((ext_vector_type(8))) unsigned short u8v;
typedef __attribute__((ext_vector_type(4))) float f4v;
typedef __attribute__((ext_vector_type(16))) float f16v;

__device__ __forceinline__ unsigned short f2bf(float f) {
    unsigned int u = __float_as_uint(f);
    u += 0x7fffu + ((u >> 16) & 1u);   // RNE
    return (unsigned short)(u >> 16);
}

__device__ __forceinline__ float fexp2(float x) { return __builtin_amdgcn_exp2f(x); }

// async 16B global->LDS (wave-uniform base + lane*16 pattern)
__device__ __forceinline__ void gld_lds16(const unsigned short* g, unsigned short* l) {
    __builtin_amdgcn_global_load_lds(
        (const __attribute__((address_space(1))) unsigned int*)g,
        (__attribute__((address_space(3))) unsigned int*)l, 16, 0, 0);
}

// ------------------------------------------------------------------ prep
// blocks [0,4096): X fp32->bf16 (float4 per thread)
// blocks [4096,5120): W transpose+convert, 64x64 tiles via fp32 LDS [64][65]
__global__ __launch_bounds__(256) void prep(
        const float* __restrict__ X,
        const float* __restrict__ Wq, const float* __restrict__ Wk,
        const float* __restrict__ Wv, const float* __restrict__ Wo,
        unsigned short* __restrict__ Xb,
        unsigned short* __restrict__ WqT, unsigned short* __restrict__ WkT,
        unsigned short* __restrict__ WvT, unsigned short* __restrict__ WoT) {
    __shared__ float lds[64][65];
    const int blk = blockIdx.x, t = threadIdx.x;
    if (blk < 4096) {
        int i = blk * 256 + t;
        float4 v = ((const float4*)X)[i];
        ushort4 r;
        r.x = f2bf(v.x); r.y = f2bf(v.y); r.z = f2bf(v.z); r.w = f2bf(v.w);
        ((ushort4*)Xb)[i] = r;
        return;
    }
    const int tb = blk - 4096;            // 0..1023
    const int w = tb >> 8;                // which W
    const int tile = tb & 255;            // 16x16 tiles of 64x64
    const int k0 = (tile >> 4) * 64, n0 = (tile & 15) * 64;
    const float* src; unsigned short* dst;
    switch (w) {
        case 0: src = Wq; dst = WqT; break;
        case 1: src = Wk; dst = WkT; break;
        case 2: src = Wv; dst = WvT; break;
        default: src = Wo; dst = WoT; break;
    }
    #pragma unroll
    for (int j = 0; j < 4; ++j) {
        int r = (t >> 4) + 16*j, c = (t & 15) * 4;
        float4 v = *(const float4*)(src + (size_t)(k0 + r) * DDIM + n0 + c);
        lds[r][c] = v.x; lds[r][c+1] = v.y; lds[r][c+2] = v.z; lds[r][c+3] = v.w;
    }
    __syncthreads();
    #pragma unroll
    for (int j = 0; j < 2; ++j) {
        int rr = (t >> 3) + 32*j, cc = (t & 7) * 8;
        u8v o;
        #pragma unroll
        for (int i = 0; i < 8; ++i) o[i] = f2bf(lds[cc + i][rr]);
        *(u8v*)(dst + (size_t)(n0 + rr) * KK + k0 + cc) = o;
    }
}

// -------------------------------------------------------------- QKV GEMM (fused)
// One block = one 128x64 tile computed for ALL THREE modes: A(X)-tile staged
// and fragment-read ONCE, B tiles for q/k/v staged per step (5 gld vs 12 for
// the same work unfused), prologue/drain amortized 3x. Grid 512 = 2 blk/CU.
// XCD swizzle: same-y (same A rows) blocks share an XCD L2.
__global__ __launch_bounds__(256) void qkv_gemm(
        const unsigned short* __restrict__ Xb,
        const unsigned short* __restrict__ WqT, const unsigned short* __restrict__ WkT,
        const unsigned short* __restrict__ WvT,
        const float* __restrict__ bq, const float* __restrict__ bk, const float* __restrict__ bv,
        unsigned short* __restrict__ Qh, unsigned short* __restrict__ Kh,
        unsigned short* __restrict__ Vt) {
    __shared__ alignas(16) unsigned short As[128*32];   // 8 KB
    __shared__ alignas(16) unsigned short Bs[3][64*32]; // 3 x 4 KB

    const int t = threadIdx.x;
    const int lane = t & 63, wave = t >> 6;
    const int wm = wave & 1, wn = wave >> 1;
    const int l15 = lane & 15, quad = lane >> 4;
    const int srow = t >> 2, schunk = (t & 3) * 8;   // staging: row 0..63, 16B chunk

    const int n = blockIdx.x;                 // 512 blocks
    const int xcd = n & 7, x = (n >> 3) & 15, youter = n >> 7;
    const int y = xcd + 8 * youter;           // 0..31; fixed XCD per y
    const int Mbase = y * 128, Nbase = x * 64;

    f4v acc[3][4][2];
    #pragma unroll
    for (int m = 0; m < 3; ++m)
        #pragma unroll
        for (int mt = 0; mt < 4; ++mt)
            #pragma unroll
            for (int nt = 0; nt < 2; ++nt)
                acc[m][mt][nt] = f4v{0.f, 0.f, 0.f, 0.f};

    const unsigned short* gA0 = Xb  + (size_t)(Mbase + srow)      * KK + schunk;
    const unsigned short* gA1 = Xb  + (size_t)(Mbase + 64 + srow) * KK + schunk;
    const unsigned short* gBq = WqT + (size_t)(Nbase + srow)      * KK + schunk;
    const unsigned short* gBk = WkT + (size_t)(Nbase + srow)      * KK + schunk;
    const unsigned short* gBv = WvT + (size_t)(Nbase + srow)      * KK + schunk;
    unsigned short* lA0 = As + t*8;
    unsigned short* lA1 = As + 64*32 + t*8;
    unsigned short* lB0 = Bs[0] + t*8;
    unsigned short* lB1 = Bs[1] + t*8;
    unsigned short* lB2 = Bs[2] + t*8;

    for (int kb = 0; kb < KK; kb += 32) {
        __syncthreads();                       // prev-tile reads complete
        gld_lds16(gA0 + kb, lA0);
        gld_lds16(gA1 + kb, lA1);
        gld_lds16(gBq + kb, lB0);
        gld_lds16(gBk + kb, lB1);
        gld_lds16(gBv + kb, lB2);
        __syncthreads();                       // vmcnt drain -> LDS populated
        s8v af[4], bfv[3][2];
        #pragma unroll
        for (int mt = 0; mt < 4; ++mt)
            af[mt] = *(const s8v*)(As + (wm*64 + mt*16 + l15)*32 + quad*8);
        #pragma unroll
        for (int m = 0; m < 3; ++m)
            #pragma unroll
            for (int nt = 0; nt < 2; ++nt)
                bfv[m][nt] = *(const s8v*)(Bs[m] + (wn*32 + nt*16 + l15)*32 + quad*8);
        #pragma unroll
        for (int m = 0; m < 3; ++m)
            #pragma unroll
            for (int mt = 0; mt < 4; ++mt)
                #pragma unroll
                for (int nt = 0; nt < 2; ++nt)
                    acc[m][mt][nt] = __builtin_amdgcn_mfma_f32_16x16x32_bf16(af[mt], bfv[m][nt], acc[m][mt][nt], 0, 0, 0);
    }

    #pragma unroll
    for (int m = 0; m < 3; ++m) {
        const float* bias   = (m == 0) ? bq : (m == 1) ? bk : bv;
        unsigned short* out = (m == 0) ? Qh : (m == 1) ? Kh : Vt;
        #pragma unroll
        for (int mt = 0; mt < 4; ++mt)
            #pragma unroll
            for (int nt = 0; nt < 2; ++nt)
                #pragma unroll
                for (int rr = 0; rr < 4; ++rr) {
                    int gm = Mbase + wm*64 + mt*16 + quad*4 + rr;   // token
                    int gn = Nbase + wn*32 + nt*16 + l15;           // feature
                    float v = acc[m][mt][nt][rr] + bias[gn];
                    int bb = gm >> 11, ll = gm & 2047;
                    int hh = gn >> 6,  dd = gn & 63;
                    if (m == 2)
                        out[((size_t)(bb*HH + hh)*HDIM + dd)*LL + ll] = f2bf(v);
                    else
                        out[((size_t)(bb*HH + hh)*LL + ll)*HDIM + dd] = f2bf(v);
                }
    }
}

// -------------------------------------------------------------- attention
// Round-10 structure verbatim (best measured: 68.4 us). 32x32x16 MFMA, grid
// 512 (16 qblks x 32 bh, XCD-swizzled); block 256 = 4 waves; wave owns 32
// q-rows; walks all 32 K-tiles of its bh. P truncation pack.
// A/B frag: m|n = lane&31, k = (lane>>5)*8 + j.
// C/D (verified m74/m101): col = lane&31, row = (reg&3) + 8*(reg>>2) + 4*(lane>>5).
__global__ __launch_bounds__(256) void attn(
        const unsigned short* __restrict__ Qh, const unsigned short* __restrict__ Kh,
        const unsigned short* __restrict__ Vt, const float* __restrict__ mask,
        unsigned short* __restrict__ ctx) {
    __shared__ alignas(16) unsigned short Ks[64*72];    // [key][kdim]   9216 B
    __shared__ alignas(16) unsigned short Vs[64*72];    // [dim][key]    9216 B
    __shared__ alignas(16) unsigned short P [4*32*72];  // per-wave [qrow][key] 18432 B

    const int t = threadIdx.x, lane = t & 63, wave = t >> 6;
    const int l31 = lane & 31, hgrp = lane >> 5;

    // XCD swizzle: n%8 fixed per bh-group -> each bh's K/V lives in one L2.
    const int n = blockIdx.x;
    const int bh = (n & 7) * 4 + ((n >> 3) & 3);   // [0,32)
    const int qblk = n >> 5;                        // [0,16)
    const int b = bh >> 4, hh = bh & 15;

    const unsigned short* Qb = Qh + (size_t)bh * LL * HDIM;
    const unsigned short* Kb = Kh + (size_t)bh * LL * HDIM;
    const unsigned short* Vb = Vt + (size_t)bh * HDIM * LL;
    const float* mb = mask + (size_t)b * LL;
    const int q0 = qblk * 128 + wave * 32;
    unsigned short* Pw = P + wave * 32 * 72;

    // staging: thread t covers row t>>2 (of 64), 32B chunk (t&3)*16
    const int srow = t >> 2, scol = (t & 3) * 16;

    // Q fragments: A[m=l31][k = hf*16 + hgrp*8 + j]
    s8v qf[4];
    #pragma unroll
    for (int hf = 0; hf < 4; ++hf)
        qf[hf] = *(const s8v*)(Qb + (size_t)(q0 + l31)*HDIM + hf*16 + hgrp*8);

    f16v o[2];
    #pragma unroll
    for (int nc = 0; nc < 2; ++nc)
        #pragma unroll
        for (int r = 0; r < 16; ++r) o[nc][r] = 0.f;
    float rs[16];
    #pragma unroll
    for (int r = 0; r < 16; ++r) rs[r] = 0.f;

    const float C1 = 0.125f * LOG2E;   // score scale folded into exp2 domain

    for (int kt = 0; kt < LL; kt += 64) {
        // global loads issued above the barrier (latency overlaps barrier wait)
        float4 ka  = *(const float4*)(Kb + (size_t)(kt + srow)*HDIM + scol);
        float4 kb2 = *(const float4*)(Kb + (size_t)(kt + srow)*HDIM + scol + 8);
        float4 va  = *(const float4*)(Vb + (size_t)srow*LL + kt + scol);
        float4 vb2 = *(const float4*)(Vb + (size_t)srow*LL + kt + scol + 8);
        float mv0 = mb[kt + l31] * LOG2E;
        float mv1 = mb[kt + 32 + l31] * LOG2E;

        __syncthreads();                 // prev-tile fragment reads complete
        *(float4*)(Ks + srow*72 + scol)     = ka;
        *(float4*)(Ks + srow*72 + scol + 8) = kb2;
        *(float4*)(Vs + srow*72 + scol)     = va;
        *(float4*)(Vs + srow*72 + scol + 8) = vb2;
        __syncthreads();                 // staging visible to all waves

        // QK^T: D rows = q, cols = keys (kc*32 + l31)
        f16v sac[2];
        #pragma unroll
        for (int kc = 0; kc < 2; ++kc) {
            #pragma unroll
            for (int r = 0; r < 16; ++r) sac[kc][r] = 0.f;
            #pragma unroll
            for (int hf = 0; hf < 4; ++hf) {
                s8v kf = *(const s8v*)(Ks + (kc*32 + l31)*72 + hf*16 + hgrp*8);
                sac[kc] = __builtin_amdgcn_mfma_f32_32x32x16_bf16(qf[hf], kf, sac[kc], 0, 0, 0);
            }
        }
        // softmax numerator (no max subtraction: scores bounded, fp32-exp2 safe)
        #pragma unroll
        for (int kc = 0; kc < 2; ++kc) {
            float mvv = kc ? mv1 : mv0;
            #pragma unroll
            for (int r = 0; r < 16; ++r) {
                float p = fexp2(sac[kc][r] * C1 + mvv);
                rs[r] += p;
                int row = (r & 3) + 8*(r >> 2) + 4*hgrp;
                Pw[row*72 + kc*32 + l31] = (unsigned short)(__float_as_uint(p) >> 16);
            }
        }
        // PV: A = P[qrow][key] (b128 reads), B = V^T[dim][key] (b128 reads)
        #pragma unroll
        for (int kt16 = 0; kt16 < 4; ++kt16) {
            s8v pf = *(const s8v*)(Pw + l31*72 + kt16*16 + hgrp*8);
            #pragma unroll
            for (int nc = 0; nc < 2; ++nc) {
                s8v vf = *(const s8v*)(Vs + (nc*32 + l31)*72 + kt16*16 + hgrp*8);
                o[nc] = __builtin_amdgcn_mfma_f32_32x32x16_bf16(pf, vf, o[nc], 0, 0, 0);
            }
        }
    }

    // row sums: reduce across the 32 lanes sharing each row set
    #pragma unroll
    for (int r = 0; r < 16; ++r) {
        float s0 = rs[r];
        s0 += __shfl_xor(s0, 1);
        s0 += __shfl_xor(s0, 2);
        s0 += __shfl_xor(s0, 4);
        s0 += __shfl_xor(s0, 8);
        s0 += __shfl_xor(s0, 16);
        rs[r] = 1.0f / s0;
    }
    #pragma unroll
    for (int r = 0; r < 16; ++r) {
        int row = (r & 3) + 8*(r >> 2) + 4*hgrp;
        int q = q0 + row;
        size_t base = ((size_t)b*LL + q)*DDIM + hh*HDIM;
        #pragma unroll
        for (int nc = 0; nc < 2; ++nc)
            ctx[base + nc*32 + l31] = f2bf(o[nc][r] * rs[r]);
    }
}

// -------------------------------------------------------------- output GEMM
// 128x64 tiles, BK=32; 1D grid 512, swizzle XCD = y%8 with x inner.
__global__ __launch_bounds__(256) void out_gemm(
        const unsigned short* __restrict__ Cb, const unsigned short* __restrict__ WoT,
        const float* __restrict__ bo, float* __restrict__ out) {
    __shared__ alignas(16) unsigned short As[128*32];
    __shared__ alignas(16) unsigned short Bs[64*32];
    const int t = threadIdx.x;
    const int lane = t & 63, wave = t >> 6;
    const int wm = wave & 1, wn = wave >> 1;
    const int l15 = lane & 15, quad = lane >> 4;
    const int srow = t >> 2, schunk = (t & 3) * 8;

    const int n = blockIdx.x;
    const int xcd = n & 7, r0 = n >> 3;     // r0 in 0..63
    const int x = r0 & 15, ysub = r0 >> 4;  // x inner -> A-tile reuse
    const int y = ysub * 8 + xcd;
    const int Mbase = y * 128, Nbase = x * 64;

    f4v acc[4][2];
    #pragma unroll
    for (int mt = 0; mt < 4; ++mt)
        #pragma unroll
        for (int nt = 0; nt < 2; ++nt)
            acc[mt][nt] = f4v{0.f, 0.f, 0.f, 0.f};

    const unsigned short* gA0 = Cb  + (size_t)(Mbase + srow)      * KK + schunk;
    const unsigned short* gA1 = Cb  + (size_t)(Mbase + 64 + srow) * KK + schunk;
    const unsigned short* gB0 = WoT + (size_t)(Nbase + srow)      * KK + schunk;
    unsigned short* lA0 = As + t*8;
    unsigned short* lA1 = As + 64*32 + t*8;
    unsigned short* lB0 = Bs + t*8;

    for (int kb = 0; kb < KK; kb += 32) {
        __syncthreads();
        gld_lds16(gA0 + kb, lA0);
        gld_lds16(gA1 + kb, lA1);
        gld_lds16(gB0 + kb, lB0);
        __syncthreads();
        s8v af[4], bfv[2];
        #pragma unroll
        for (int mt = 0; mt < 4; ++mt)
            af[mt] = *(const s8v*)(As + (wm*64 + mt*16 + l15)*32 + quad*8);
        #pragma unroll
        for (int nt = 0; nt < 2; ++nt)
            bfv[nt] = *(const s8v*)(Bs + (wn*32 + nt*16 + l15)*32 + quad*8);
        #pragma unroll
        for (int mt = 0; mt < 4; ++mt)
            #pragma unroll
            for (int nt = 0; nt < 2; ++nt)
                acc[mt][nt] = __builtin_amdgcn_mfma_f32_16x16x32_bf16(af[mt], bfv[nt], acc[mt][nt], 0, 0, 0);
    }

    #pragma unroll
    for (int mt = 0; mt < 4; ++mt)
        #pragma unroll
        for (int nt = 0; nt < 2; ++nt)
            #pragma unroll
            for (int rr = 0; rr < 4; ++rr) {
                int gm = Mbase + wm*64 + mt*16 + quad*4 + rr;
                int gn = Nbase + wn*32 + nt*16 + l15;
                out[(size_t)gm*DDIM + gn] = acc[mt][nt][rr] + bo[gn];
            }
}

// ---------------------------------------------------------------- launcher
extern "C" void kernel_launch(void* const* d_in, const int* in_sizes, int n_in,
                              void* d_out, int out_size, void* d_ws, size_t ws_size,
                              hipStream_t stream) {
    const float* X    = (const float*)d_in[0];
    const float* mask = (const float*)d_in[1];
    const float* Wq   = (const float*)d_in[2];
    const float* bq   = (const float*)d_in[3];
    const float* Wk   = (const float*)d_in[4];
    const float* bk   = (const float*)d_in[5];
    const float* Wv   = (const float*)d_in[6];
    const float* bv   = (const float*)d_in[7];
    const float* Wo   = (const float*)d_in[8];
    const float* bo   = (const float*)d_in[9];
    float* out = (float*)d_out;

    char* ws = (char*)d_ws;
    unsigned short* Xb  = (unsigned short*)(ws);              // 8 MB (reused as ctx)
    unsigned short* WqT = (unsigned short*)(ws + (8u  << 20));
    unsigned short* WkT = (unsigned short*)(ws + (10u << 20));
    unsigned short* WvT = (unsigned short*)(ws + (12u << 20));
    unsigned short* WoT = (unsigned short*)(ws + (14u << 20));
    unsigned short* Qh  = (unsigned short*)(ws + (16u << 20)); // 8 MB
    unsigned short* Kh  = (unsigned short*)(ws + (24u << 20)); // 8 MB
    unsigned short* Vt  = (unsigned short*)(ws + (32u << 20)); // 8 MB
    unsigned short* Cb  = Xb;                                  // ctx bf16, reuse X slot

    prep     <<<dim3(5120),  dim3(256), 0, stream>>>(X, Wq, Wk, Wv, Wo, Xb, WqT, WkT, WvT, WoT);
    qkv_gemm <<<dim3(512),   dim3(256), 0, stream>>>(Xb, WqT, WkT, WvT, bq, bk, bv, Qh, Kh, Vt);
    attn     <<<dim3(512),   dim3(256), 0, stream>>>(Qh, Kh, Vt, mask, Cb);
    out_gemm <<<dim3(512),   dim3(256), 0, stream>>>(Cb, WoT, bo, out);
}

// Round 14
// 209.323 us; speedup vs baseline: 1.1300x; 1.1300x over previous
//
#include <hip/hip_runtime.h>

#define BB 2
#define LL 2048
#define DDIM 1024
#define HH 16
#define HDIM 64
#define MM (BB*LL)   // 4096
#define KK 1024
#define LOG2E 1.44269504f

typedef __attribute__((ext_vector_type(8))) short s8v;
typedef __attribute__((ext_vector_type(8))) unsigned short u8v;
typedef __attribute__((ext_vector_type(4))) float f4v;
typedef __attribute__((ext_vector_type(16))) float f16v;

__device__ __forceinline__ unsigned short f2bf(float f) {
    unsigned int u = __float_as_uint(f);
    u += 0x7fffu + ((u >> 16) & 1u);   // RNE
    return (unsigned short)(u >> 16);
}

__device__ __forceinline__ float fexp2(float x) { return __builtin_amdgcn_exp2f(x); }

// async 16B global->LDS (wave-uniform base + lane*16 pattern)
__device__ __forceinline__ void gld_lds16(const unsigned short* g, unsigned short* l) {
    __builtin_amdgcn_global_load_lds(
        (const __attribute__((address_space(1))) unsigned int*)g,
        (__attribute__((address_space(3))) unsigned int*)l, 16, 0, 0);
}

// ------------------------------------------------------------------ prep
// blocks [0,4096): X fp32->bf16 (float4 per thread)
// blocks [4096,5120): W transpose+convert, 64x64 tiles via fp32 LDS [64][65]
__global__ __launch_bounds__(256) void prep(
        const float* __restrict__ X,
        const float* __restrict__ Wq, const float* __restrict__ Wk,
        const float* __restrict__ Wv, const float* __restrict__ Wo,
        unsigned short* __restrict__ Xb,
        unsigned short* __restrict__ WqT, unsigned short* __restrict__ WkT,
        unsigned short* __restrict__ WvT, unsigned short* __restrict__ WoT) {
    __shared__ float lds[64][65];
    const int blk = blockIdx.x, t = threadIdx.x;
    if (blk < 4096) {
        int i = blk * 256 + t;
        float4 v = ((const float4*)X)[i];
        ushort4 r;
        r.x = f2bf(v.x); r.y = f2bf(v.y); r.z = f2bf(v.z); r.w = f2bf(v.w);
        ((ushort4*)Xb)[i] = r;
        return;
    }
    const int tb = blk - 4096;            // 0..1023
    const int w = tb >> 8;                // which W
    const int tile = tb & 255;            // 16x16 tiles of 64x64
    const int k0 = (tile >> 4) * 64, n0 = (tile & 15) * 64;
    const float* src; unsigned short* dst;
    switch (w) {
        case 0: src = Wq; dst = WqT; break;
        case 1: src = Wk; dst = WkT; break;
        case 2: src = Wv; dst = WvT; break;
        default: src = Wo; dst = WoT; break;
    }
    #pragma unroll
    for (int j = 0; j < 4; ++j) {
        int r = (t >> 4) + 16*j, c = (t & 15) * 4;
        float4 v = *(const float4*)(src + (size_t)(k0 + r) * DDIM + n0 + c);
        lds[r][c] = v.x; lds[r][c+1] = v.y; lds[r][c+2] = v.z; lds[r][c+3] = v.w;
    }
    __syncthreads();
    #pragma unroll
    for (int j = 0; j < 2; ++j) {
        int rr = (t >> 3) + 32*j, cc = (t & 7) * 8;
        u8v o;
        #pragma unroll
        for (int i = 0; i < 8; ++i) o[i] = f2bf(lds[cc + i][rr]);
        *(u8v*)(dst + (size_t)(n0 + rr) * KK + k0 + cc) = o;
    }
}

// ---------------------------------------------------------------- GEMM core
// m97-style BK=32: C[128x128] = A[M,1024] @ BT[N,1024]^T ; 4 waves, 64x64 each.
__device__ __forceinline__ void gemm_core(const unsigned short* __restrict__ A,
                                          const unsigned short* __restrict__ BT,
                                          int Mbase, int Nbase,
                                          unsigned short* As, unsigned short* Bs,
                                          f4v acc[4][4]) {
    const int t = threadIdx.x;
    const int lane = t & 63, wave = t >> 6;
    const int wm = wave & 1, wn = wave >> 1;
    const int l15 = lane & 15, quad = lane >> 4;
    const int srow = t >> 2, schunk = (t & 3) * 8;   // staging: row 0..63, 16B chunk

    #pragma unroll
    for (int mt = 0; mt < 4; ++mt)
        #pragma unroll
        for (int nt = 0; nt < 4; ++nt)
            acc[mt][nt] = f4v{0.f, 0.f, 0.f, 0.f};

    const unsigned short* gA0 = A  + (size_t)(Mbase + srow)      * KK + schunk;
    const unsigned short* gA1 = A  + (size_t)(Mbase + 64 + srow) * KK + schunk;
    const unsigned short* gB0 = BT + (size_t)(Nbase + srow)      * KK + schunk;
    const unsigned short* gB1 = BT + (size_t)(Nbase + 64 + srow) * KK + schunk;
    unsigned short* lA0 = As + t*8;
    unsigned short* lA1 = As + 64*32 + t*8;
    unsigned short* lB0 = Bs + t*8;
    unsigned short* lB1 = Bs + 64*32 + t*8;

    for (int kb = 0; kb < KK; kb += 32) {
        __syncthreads();                       // prev-tile reads complete
        gld_lds16(gA0 + kb, lA0);
        gld_lds16(gA1 + kb, lA1);
        gld_lds16(gB0 + kb, lB0);
        gld_lds16(gB1 + kb, lB1);
        __syncthreads();                       // vmcnt drain -> LDS populated
        s8v af[4], bfv[4];
        #pragma unroll
        for (int mt = 0; mt < 4; ++mt)
            af[mt] = *(const s8v*)(As + (wm*64 + mt*16 + l15)*32 + quad*8);
        #pragma unroll
        for (int nt = 0; nt < 4; ++nt)
            bfv[nt] = *(const s8v*)(Bs + (wn*64 + nt*16 + l15)*32 + quad*8);
        #pragma unroll
        for (int mt = 0; mt < 4; ++mt)
            #pragma unroll
            for (int nt = 0; nt < 4; ++nt)
                acc[mt][nt] = __builtin_amdgcn_mfma_f32_16x16x32_bf16(af[mt], bfv[nt], acc[mt][nt], 0, 0, 0);
    }
}

// -------------------------------------------------------------- QKV GEMM
// Round-10 unfused (best measured): 1D grid 768, XCD-tiled swizzle; mode
// innermost (A-tile L2 reuse). 0->Qh [B,H,L,HD], 1->Kh, 2->Vt [B,H,HD,L]
__global__ __launch_bounds__(256) void qkv_gemm(
        const unsigned short* __restrict__ Xb,
        const unsigned short* __restrict__ WqT, const unsigned short* __restrict__ WkT,
        const unsigned short* __restrict__ WvT,
        const float* __restrict__ bq, const float* __restrict__ bk, const float* __restrict__ bv,
        unsigned short* __restrict__ Qh, unsigned short* __restrict__ Kh,
        unsigned short* __restrict__ Vt) {
    __shared__ alignas(16) unsigned short As[128*32];
    __shared__ alignas(16) unsigned short Bs[128*32];

    const int n = blockIdx.x;
    const int xcd = n & 7, r = n >> 3;      // r in 0..95
    const int gx = xcd >> 1, gy = xcd & 1;
    const int mode = r % 3;
    const int r2 = r / 3;                   // 0..31
    const int x = gx*2 + (r2 & 1);
    const int y = gy*16 + (r2 >> 1);

    const unsigned short* BT = (mode == 0) ? WqT : (mode == 1) ? WkT : WvT;
    const float* bias        = (mode == 0) ? bq  : (mode == 1) ? bk  : bv;
    unsigned short* out      = (mode == 0) ? Qh  : (mode == 1) ? Kh  : Vt;
    const int Mbase = y * 128, Nbase = x * 128;

    f4v acc[4][4];
    gemm_core(Xb, BT, Mbase, Nbase, As, Bs, acc);

    const int lane = threadIdx.x & 63, wave = threadIdx.x >> 6;
    const int wm = wave & 1, wn = wave >> 1, l15 = lane & 15, quad = lane >> 4;
    #pragma unroll
    for (int mt = 0; mt < 4; ++mt)
        #pragma unroll
        for (int nt = 0; nt < 4; ++nt)
            #pragma unroll
            for (int rr = 0; rr < 4; ++rr) {
                int gm = Mbase + wm*64 + mt*16 + quad*4 + rr;  // token
                int gn = Nbase + wn*64 + nt*16 + l15;          // feature
                float v = acc[mt][nt][rr] + bias[gn];
                int bb = gm >> 11, ll = gm & 2047;
                int hh = gn >> 6,  dd = gn & 63;
                if (mode == 2)
                    out[((size_t)(bb*HH + hh)*HDIM + dd)*LL + ll] = f2bf(v);
                else
                    out[((size_t)(bb*HH + hh)*LL + ll)*HDIM + dd] = f2bf(v);
            }
}

// -------------------------------------------------------------- attention
// Round-10 dataflow + DOUBLE-BUFFERED K/V staging: loads for tile i+1 issued
// at top of iter i, ds_write AFTER compute (vmcnt wait hidden behind ~700 cyc
// of compute), ONE barrier per iteration (was 2 + exposed load latency).
// LDS: 2 x (Ks+Vs) 36864 B + P 18432 B = 55296 B -> 2 blocks/CU (unchanged).
// A/B frag: m|n = lane&31, k = (lane>>5)*8 + j.
// C/D (verified m74/m101): col = lane&31, row = (reg&3) + 8*(reg>>2) + 4*(lane>>5).
__global__ __launch_bounds__(256) void attn(
        const unsigned short* __restrict__ Qh, const unsigned short* __restrict__ Kh,
        const unsigned short* __restrict__ Vt, const float* __restrict__ mask,
        unsigned short* __restrict__ ctx) {
    __shared__ alignas(16) unsigned short KV[2][2*64*72];  // [buf][Ks|Vs]
    __shared__ alignas(16) unsigned short P [4*32*72];     // per-wave [qrow][key]

    const int t = threadIdx.x, lane = t & 63, wave = t >> 6;
    const int l31 = lane & 31, hgrp = lane >> 5;

    // XCD swizzle: n%8 fixed per bh-group -> each bh's K/V lives in one L2.
    const int n = blockIdx.x;
    const int bh = (n & 7) * 4 + ((n >> 3) & 3);   // [0,32)
    const int qblk = n >> 5;                        // [0,16)
    const int b = bh >> 4, hh = bh & 15;

    const unsigned short* Qb = Qh + (size_t)bh * LL * HDIM;
    const unsigned short* Kb = Kh + (size_t)bh * LL * HDIM;
    const unsigned short* Vb = Vt + (size_t)bh * HDIM * LL;
    const float* mb = mask + (size_t)b * LL;
    const int q0 = qblk * 128 + wave * 32;
    unsigned short* Pw = P + wave * 32 * 72;

    // staging: thread t covers row t>>2 (of 64), 16B chunk (t&3)*16... (x2 halves)
    const int srow = t >> 2, scol = (t & 3) * 16;

    // Q fragments: A[m=l31][k = hf*16 + hgrp*8 + j]
    s8v qf[4];
    #pragma unroll
    for (int hf = 0; hf < 4; ++hf)
        qf[hf] = *(const s8v*)(Qb + (size_t)(q0 + l31)*HDIM + hf*16 + hgrp*8);

    f16v o[2];
    #pragma unroll
    for (int nc = 0; nc < 2; ++nc)
        #pragma unroll
        for (int r = 0; r < 16; ++r) o[nc][r] = 0.f;
    float rs[16];
    #pragma unroll
    for (int r = 0; r < 16; ++r) rs[r] = 0.f;

    const float C1 = 0.125f * LOG2E;   // score scale folded into exp2 domain

    // ---- prologue: tile 0 into buf 0 ----
    float4 ka  = *(const float4*)(Kb + (size_t)srow*HDIM + scol);
    float4 kb2 = *(const float4*)(Kb + (size_t)srow*HDIM + scol + 8);
    float4 va  = *(const float4*)(Vb + (size_t)srow*LL + scol);
    float4 vb2 = *(const float4*)(Vb + (size_t)srow*LL + scol + 8);
    float mvc0 = mb[l31] * LOG2E;
    float mvc1 = mb[32 + l31] * LOG2E;
    {
        unsigned short* Kn = KV[0];
        unsigned short* Vn = KV[0] + 64*72;
        *(float4*)(Kn + srow*72 + scol)     = ka;
        *(float4*)(Kn + srow*72 + scol + 8) = kb2;
        *(float4*)(Vn + srow*72 + scol)     = va;
        *(float4*)(Vn + srow*72 + scol + 8) = vb2;
    }
    __syncthreads();

    for (int i = 0; i < 32; ++i) {
        const int kt = i * 64;
        const unsigned short* Kc = KV[i & 1];
        const unsigned short* Vc = KV[i & 1] + 64*72;

        // issue next tile's loads (consumed only after this iter's compute)
        float mvn0 = 0.f, mvn1 = 0.f;
        if (i < 31) {
            ka  = *(const float4*)(Kb + (size_t)(kt + 64 + srow)*HDIM + scol);
            kb2 = *(const float4*)(Kb + (size_t)(kt + 64 + srow)*HDIM + scol + 8);
            va  = *(const float4*)(Vb + (size_t)srow*LL + kt + 64 + scol);
            vb2 = *(const float4*)(Vb + (size_t)srow*LL + kt + 64 + scol + 8);
            mvn0 = mb[kt + 64 + l31];
            mvn1 = mb[kt + 96 + l31];
        }

        // QK^T: D rows = q, cols = keys (kc*32 + l31)
        f16v sac[2];
        #pragma unroll
        for (int kc = 0; kc < 2; ++kc) {
            #pragma unroll
            for (int r = 0; r < 16; ++r) sac[kc][r] = 0.f;
            #pragma unroll
            for (int hf = 0; hf < 4; ++hf) {
                s8v kf = *(const s8v*)(Kc + (kc*32 + l31)*72 + hf*16 + hgrp*8);
                sac[kc] = __builtin_amdgcn_mfma_f32_32x32x16_bf16(qf[hf], kf, sac[kc], 0, 0, 0);
            }
        }
        // softmax numerator (no max subtraction: scores bounded, fp32-exp2 safe)
        #pragma unroll
        for (int kc = 0; kc < 2; ++kc) {
            float mvv = kc ? mvc1 : mvc0;
            #pragma unroll
            for (int r = 0; r < 16; ++r) {
                float p = fexp2(sac[kc][r] * C1 + mvv);
                rs[r] += p;
                int row = (r & 3) + 8*(r >> 2) + 4*hgrp;
                Pw[row*72 + kc*32 + l31] = (unsigned short)(__float_as_uint(p) >> 16);
            }
        }
        // PV: A = P[qrow][key] (b128 reads), B = V^T[dim][key] (b128 reads)
        #pragma unroll
        for (int kt16 = 0; kt16 < 4; ++kt16) {
            s8v pf = *(const s8v*)(Pw + l31*72 + kt16*16 + hgrp*8);
            #pragma unroll
            for (int nc = 0; nc < 2; ++nc) {
                s8v vf = *(const s8v*)(Vc + (nc*32 + l31)*72 + kt16*16 + hgrp*8);
                o[nc] = __builtin_amdgcn_mfma_f32_32x32x16_bf16(pf, vf, o[nc], 0, 0, 0);
            }
        }

        // stage next tile (vmcnt wait here — covered by the compute above),
        // then ONE barrier: publishes buf (i+1)&1; old readers of it finished
        // before the previous barrier.
        if (i < 31) {
            unsigned short* Kn = KV[(i + 1) & 1];
            unsigned short* Vn = KV[(i + 1) & 1] + 64*72;
            *(float4*)(Kn + srow*72 + scol)     = ka;
            *(float4*)(Kn + srow*72 + scol + 8) = kb2;
            *(float4*)(Vn + srow*72 + scol)     = va;
            *(float4*)(Vn + srow*72 + scol + 8) = vb2;
            mvc0 = mvn0 * LOG2E;
            mvc1 = mvn1 * LOG2E;
            __syncthreads();
        }
    }

    // row sums: reduce across the 32 lanes sharing each row set
    #pragma unroll
    for (int r = 0; r < 16; ++r) {
        float s0 = rs[r];
        s0 += __shfl_xor(s0, 1);
        s0 += __shfl_xor(s0, 2);
        s0 += __shfl_xor(s0, 4);
        s0 += __shfl_xor(s0, 8);
        s0 += __shfl_xor(s0, 16);
        rs[r] = 1.0f / s0;
    }
    #pragma unroll
    for (int r = 0; r < 16; ++r) {
        int row = (r & 3) + 8*(r >> 2) + 4*hgrp;
        int q = q0 + row;
        size_t base = ((size_t)b*LL + q)*DDIM + hh*HDIM;
        #pragma unroll
        for (int nc = 0; nc < 2; ++nc)
            ctx[base + nc*32 + l31] = f2bf(o[nc][r] * rs[r]);
    }
}

// -------------------------------------------------------------- output GEMM
// 128x64 tiles, BK=32; 1D grid 512, swizzle XCD = y%8 with x inner.
__global__ __launch_bounds__(256) void out_gemm(
        const unsigned short* __restrict__ Cb, const unsigned short* __restrict__ WoT,
        const float* __restrict__ bo, float* __restrict__ out) {
    __shared__ alignas(16) unsigned short As[128*32];
    __shared__ alignas(16) unsigned short Bs[64*32];
    const int t = threadIdx.x;
    const int lane = t & 63, wave = t >> 6;
    const int wm = wave & 1, wn = wave >> 1;
    const int l15 = lane & 15, quad = lane >> 4;
    const int srow = t >> 2, schunk = (t & 3) * 8;

    const int n = blockIdx.x;
    const int xcd = n & 7, r0 = n >> 3;     // r0 in 0..63
    const int x = r0 & 15, ysub = r0 >> 4;  // x inner -> A-tile reuse
    const int y = ysub * 8 + xcd;
    const int Mbase = y * 128, Nbase = x * 64;

    f4v acc[4][2];
    #pragma unroll
    for (int mt = 0; mt < 4; ++mt)
        #pragma unroll
        for (int nt = 0; nt < 2; ++nt)
            acc[mt][nt] = f4v{0.f, 0.f, 0.f, 0.f};

    const unsigned short* gA0 = Cb  + (size_t)(Mbase + srow)      * KK + schunk;
    const unsigned short* gA1 = Cb  + (size_t)(Mbase + 64 + srow) * KK + schunk;
    const unsigned short* gB0 = WoT + (size_t)(Nbase + srow)      * KK + schunk;
    unsigned short* lA0 = As + t*8;
    unsigned short* lA1 = As + 64*32 + t*8;
    unsigned short* lB0 = Bs + t*8;

    for (int kb = 0; kb < KK; kb += 32) {
        __syncthreads();
        gld_lds16(gA0 + kb, lA0);
        gld_lds16(gA1 + kb, lA1);
        gld_lds16(gB0 + kb, lB0);
        __syncthreads();
        s8v af[4], bfv[2];
        #pragma unroll
        for (int mt = 0; mt < 4; ++mt)
            af[mt] = *(const s8v*)(As + (wm*64 + mt*16 + l15)*32 + quad*8);
        #pragma unroll
        for (int nt = 0; nt < 2; ++nt)
            bfv[nt] = *(const s8v*)(Bs + (wn*32 + nt*16 + l15)*32 + quad*8);
        #pragma unroll
        for (int mt = 0; mt < 4; ++mt)
            #pragma unroll
            for (int nt = 0; nt < 2; ++nt)
                acc[mt][nt] = __builtin_amdgcn_mfma_f32_16x16x32_bf16(af[mt], bfv[nt], acc[mt][nt], 0, 0, 0);
    }

    #pragma unroll
    for (int mt = 0; mt < 4; ++mt)
        #pragma unroll
        for (int nt = 0; nt < 2; ++nt)
            #pragma unroll
            for (int rr = 0; rr < 4; ++rr) {
                int gm = Mbase + wm*64 + mt*16 + quad*4 + rr;
                int gn = Nbase + wn*32 + nt*16 + l15;
                out[(size_t)gm*DDIM + gn] = acc[mt][nt][rr] + bo[gn];
            }
}

// ---------------------------------------------------------------- launcher
extern "C" void kernel_launch(void* const* d_in, const int* in_sizes, int n_in,
                              void* d_out, int out_size, void* d_ws, size_t ws_size,
                              hipStream_t stream) {
    const float* X    = (const float*)d_in[0];
    const float* mask = (const float*)d_in[1];
    const float* Wq   = (const float*)d_in[2];
    const float* bq   = (const float*)d_in[3];
    const float* Wk   = (const float*)d_in[4];
    const float* bk   = (const float*)d_in[5];
    const float* Wv   = (const float*)d_in[6];
    const float* bv   = (const float*)d_in[7];
    const float* Wo   = (const float*)d_in[8];
    const float* bo   = (const float*)d_in[9];
    float* out = (float*)d_out;

    char* ws = (char*)d_ws;
    unsigned short* Xb  = (unsigned short*)(ws);              // 8 MB (reused as ctx)
    unsigned short* WqT = (unsigned short*)(ws + (8u  << 20));
    unsigned short* WkT = (unsigned short*)(ws + (10u << 20));
    unsigned short* WvT = (unsigned short*)(ws + (12u << 20));
    unsigned short* WoT = (unsigned short*)(ws + (14u << 20));
    unsigned short* Qh  = (unsigned short*)(ws + (16u << 20)); // 8 MB
    unsigned short* Kh  = (unsigned short*)(ws + (24u << 20)); // 8 MB
    unsigned short* Vt  = (unsigned short*)(ws + (32u << 20)); // 8 MB
    unsigned short* Cb  = Xb;                                  // ctx bf16, reuse X slot

    prep     <<<dim3(5120),  dim3(256), 0, stream>>>(X, Wq, Wk, Wv, Wo, Xb, WqT, WkT, WvT, WoT);
    qkv_gemm <<<dim3(768),   dim3(256), 0, stream>>>(Xb, WqT, WkT, WvT, bq, bk, bv, Qh, Kh, Vt);
    attn     <<<dim3(512),   dim3(256), 0, stream>>>(Qh, Kh, Vt, mask, Cb);
    out_gemm <<<dim3(512),   dim3(256), 0, stream>>>(Cb, WoT, bo, out);
}